// Round 2
// baseline (265.215 us; speedup 1.0000x reference)
//
#include <hip/hip_runtime.h>
#include <cmath>

#define WIN 11
#define HALO 5
#define IMG 512
#define TW 64
#define TH 16
#define RH (TH + 2*HALO)   /* 26 h-blurred rows needed per tile */
#define SH 68              /* h-buffer row stride: 68%32=4 -> rows offset 4 banks, conflict-free */
#define NIMG 48            /* 16 batch * 3 channels */
#define NPIX (16.0 * 3.0 * 512.0 * 512.0)

struct GaussW { float w[WIN]; };

__global__ void __launch_bounds__(64) zero_kernel(float* out) {
    if (threadIdx.x == 0) out[0] = 0.f;
}

// One block = one 64x16 output tile. Stage A: 208 threads each produce 8
// horizontally-blurred outputs for one of 26 rows (direct global loads, no
// input staging in LDS). Stage B: vertical blur + SSIM + reduce.
__global__ void __launch_bounds__(256) ssim_tile_kernel(
        const float* __restrict__ xin, const float* __restrict__ yin,
        float* __restrict__ out_acc, GaussW W) {
    __shared__ float hx [RH * SH];
    __shared__ float hy [RH * SH];
    __shared__ float hxx[RH * SH];
    __shared__ float hyy[RH * SH];
    __shared__ float hxy[RH * SH];
    __shared__ float wsum[4];

    const int tid = threadIdx.x;
    const size_t ibase = (size_t)blockIdx.z * (IMG * IMG);
    const float* __restrict__ xb = xin + ibase;
    const float* __restrict__ yb = yin + ibase;

    // ---- Stage A: horizontal blur of 5 fields, 8 outputs/thread.
    if (tid < RH * (TW / 8)) {
        const int r  = tid >> 3;          // 0..25
        const int cg = tid & 7;           // 0..7
        const int gy  = blockIdx.y * TH - HALO + r;
        const int gx0 = blockIdx.x * TW - HALO + cg * 8;   // window cols gx0..gx0+17

        float xv[18], yv[18];
        const bool rowok = ((unsigned)gy < IMG);
        const float* xr = xb + (size_t)gy * IMG;
        const float* yr = yb + (size_t)gy * IMG;
        #pragma unroll
        for (int j = 0; j < 18; ++j) {
            int gx = gx0 + j;
            bool ok = rowok && ((unsigned)gx < IMG);
            xv[j] = ok ? xr[gx] : 0.f;
            yv[j] = ok ? yr[gx] : 0.f;
        }

        float ax[8]  = {0,0,0,0,0,0,0,0}, ay[8]  = {0,0,0,0,0,0,0,0};
        float axx[8] = {0,0,0,0,0,0,0,0}, ayy[8] = {0,0,0,0,0,0,0,0};
        float axy[8] = {0,0,0,0,0,0,0,0};

        // accumulate-by-input: each input element's products computed ONCE
        #pragma unroll
        for (int j = 0; j < 18; ++j) {
            float xs = xv[j], ys = yv[j];
            float xx = xs * xs, yy = ys * ys, xy = xs * ys;
            #pragma unroll
            for (int o = 0; o < 8; ++o) {
                int k = j - o;                 // tap index, const after unroll
                if (k >= 0 && k < WIN) {
                    float wk = W.w[k];
                    ax[o]  += wk * xs;
                    ay[o]  += wk * ys;
                    axx[o] += wk * xx;
                    ayy[o] += wk * yy;
                    axy[o] += wk * xy;
                }
            }
        }

        const int ob = r * SH + cg * 8;
        *(float4*)&hx [ob]     = make_float4(ax[0],  ax[1],  ax[2],  ax[3]);
        *(float4*)&hx [ob + 4] = make_float4(ax[4],  ax[5],  ax[6],  ax[7]);
        *(float4*)&hy [ob]     = make_float4(ay[0],  ay[1],  ay[2],  ay[3]);
        *(float4*)&hy [ob + 4] = make_float4(ay[4],  ay[5],  ay[6],  ay[7]);
        *(float4*)&hxx[ob]     = make_float4(axx[0], axx[1], axx[2], axx[3]);
        *(float4*)&hxx[ob + 4] = make_float4(axx[4], axx[5], axx[6], axx[7]);
        *(float4*)&hyy[ob]     = make_float4(ayy[0], ayy[1], ayy[2], ayy[3]);
        *(float4*)&hyy[ob + 4] = make_float4(ayy[4], ayy[5], ayy[6], ayy[7]);
        *(float4*)&hxy[ob]     = make_float4(axy[0], axy[1], axy[2], axy[3]);
        *(float4*)&hxy[ob + 4] = make_float4(axy[4], axy[5], axy[6], axy[7]);
    }
    __syncthreads();

    // ---- Stage B: vertical blur (4 rows/thread, shared 14-row window) + SSIM
    const int c  = tid & (TW - 1);
    const int r0 = (tid >> 6) << 2;   // 0,4,8,12

    float mx[4]  = {0,0,0,0}, my[4]  = {0,0,0,0};
    float vxx[4] = {0,0,0,0}, vyy[4] = {0,0,0,0}, vxy[4] = {0,0,0,0};

    auto vblur4 = [&](const float* buf, float acc[4]) {
        float v[14];
        #pragma unroll
        for (int k = 0; k < 14; ++k) v[k] = buf[(r0 + k) * SH + c];
        #pragma unroll
        for (int k = 0; k < WIN; ++k) {
            float wk = W.w[k];
            #pragma unroll
            for (int o = 0; o < 4; ++o) acc[o] += wk * v[k + o];
        }
    };
    vblur4(hx,  mx);
    vblur4(hy,  my);
    vblur4(hxx, vxx);
    vblur4(hyy, vyy);
    vblur4(hxy, vxy);

    const float C1 = 0.01f * 0.01f;
    const float C2 = 0.03f * 0.03f;
    float local = 0.f;
    #pragma unroll
    for (int o = 0; o < 4; ++o) {
        float mux = mx[o], muy = my[o];
        float mux2 = mux * mux, muy2 = muy * muy, muxy = mux * muy;
        float sxx_ = vxx[o] - mux2;
        float syy_ = vyy[o] - muy2;
        float sxy_ = vxy[o] - muxy;
        float num = (2.f * muxy + C1) * (2.f * sxy_ + C2);
        float den = (mux2 + muy2 + C1) * (sxx_ + syy_ + C2);
        local += num / (den + 1e-8f);
    }

    // ---- block reduce: wave shuffle, then one atomic per block
    #pragma unroll
    for (int off = 32; off > 0; off >>= 1)
        local += __shfl_down(local, off, 64);
    if ((tid & 63) == 0) wsum[tid >> 6] = local;
    __syncthreads();
    if (tid == 0)
        atomicAdd(out_acc, wsum[0] + wsum[1] + wsum[2] + wsum[3]);
}

__global__ void __launch_bounds__(64) finish_kernel(float* out) {
    if (threadIdx.x == 0)
        out[0] = 1.0f - out[0] * (float)(1.0 / NPIX);
}

extern "C" void kernel_launch(void* const* d_in, const int* in_sizes, int n_in,
                              void* d_out, int out_size, void* d_ws, size_t ws_size,
                              hipStream_t stream) {
    const float* x = (const float*)d_in[0];
    const float* y = (const float*)d_in[1];
    float* out = (float*)d_out;

    GaussW gw;
    double g[WIN], s = 0.0;
    for (int i = 0; i < WIN; ++i) {
        double d = (double)(i - WIN / 2);
        g[i] = exp(-(d * d) / (2.0 * 1.5 * 1.5));
        s += g[i];
    }
    for (int i = 0; i < WIN; ++i) gw.w[i] = (float)(g[i] / s);

    hipLaunchKernelGGL(zero_kernel, dim3(1), dim3(64), 0, stream, out);
    dim3 grid(IMG / TW, IMG / TH, NIMG);
    hipLaunchKernelGGL(ssim_tile_kernel, grid, dim3(256), 0, stream, x, y, out, gw);
    hipLaunchKernelGGL(finish_kernel, dim3(1), dim3(64), 0, stream, out);
}